// Round 2
// baseline (417.879 us; speedup 1.0000x reference)
//
#include <hip/hip_runtime.h>
#include <hip/hip_bf16.h>

// lw(x) = -0.5 * ( ||x(I-A) - b||^2 + ||xA + (b - theta)||^2 )
// i.e. G = x . U with U = [I-A | A]  (64 x 128),  column consts cvec = [-b | b-theta]
// lw = -0.5 * sum_n (G[n] + cvec[n])^2, with cvec folded into the MFMA accumulator init.
// ELBO = -(1/1024) * sum_rows softmax-weighted mean of lw over 1024 consecutive samples.
//
// R1: finish_kernel fused into main_kernel via deterministic last-block reduce
// (ticket counter zeroed by prep). Saves one launch + 1-block tail kernel.
// R2: identical resubmit — R1 bench died to container-acquisition infra failure,
// not a kernel fault (no spin-wait, ctr re-zeroed each launch, no deadlock path).

typedef __attribute__((ext_vector_type(8))) short short8;   // 8 bf16 = 4 VGPRs (MFMA A/B frag)
typedef __attribute__((ext_vector_type(4))) float floatx4;  // MFMA C/D frag

#define WS_UT  0        // ushort[128*64] : U^T bf16, Ut[n*64+k] = U[k][n]
#define WS_CV  16384    // float[128]     : column constants
#define WS_R   17920    // float[1024]    : per-softmax-row results
#define WS_CTR 22016    // unsigned int   : last-block ticket

__device__ __forceinline__ short bf16r(float f) {
  __hip_bfloat16 h = __float2bfloat16(f);   // RNE
  short r; __builtin_memcpy(&r, &h, 2); return r;
}

__device__ __forceinline__ short8 cvt_bf16x8(float4 a, float4 b) {
  short8 r;
  r[0]=bf16r(a.x); r[1]=bf16r(a.y); r[2]=bf16r(a.z); r[3]=bf16r(a.w);
  r[4]=bf16r(b.x); r[5]=bf16r(b.y); r[6]=bf16r(b.z); r[7]=bf16r(b.w);
  return r;
}

__global__ void prep_kernel(const float* __restrict__ A, const float* __restrict__ b,
                            const float* __restrict__ th,
                            unsigned short* __restrict__ Ut, float* __restrict__ cvec,
                            unsigned int* __restrict__ ctr) {
  const int i = blockIdx.x * 256 + threadIdx.x;   // 8192 threads: k = i>>7, n = i&127
  const int k = i >> 7, n = i & 127;
  float u;
  if (n < 64) u = (k == n ? 1.f : 0.f) - A[k*64 + n];
  else        u = A[k*64 + (n - 64)];
  __hip_bfloat16 h = __float2bfloat16(u);
  unsigned short us; __builtin_memcpy(&us, &h, 2);
  Ut[n*64 + k] = us;                               // transposed for contiguous B-frag loads
  if (i < 128) cvec[i] = (i < 64) ? -b[i] : (b[i - 64] - th[i - 64]);
  if (i == 0) *ctr = 0u;                           // ticket for fused finish (stream-ordered)
}

// One block per softmax row (1024 samples). 256 threads = 4 waves; each wave does
// 16 tiles of 16 samples. MFMA 16x16x32 bf16: A = x tile, B = U (resident in regs).
// Last block (device-wide ticket) performs the final reduction over rbuf -> out.
__global__ __launch_bounds__(256) void main_kernel(
    const float* __restrict__ x, const unsigned short* __restrict__ Ut,
    const float* __restrict__ cvec, float* __restrict__ rbuf,
    unsigned int* __restrict__ ctr, float* __restrict__ out) {
  __shared__ __align__(16) float lws[1024];
  __shared__ float wredA[4], wredB[4], wredC[4];
  __shared__ int lastflag;

  const int tid = threadIdx.x;
  const int w = tid >> 6, l = tid & 63, q = l >> 4, s = l & 15;
  const int n0 = blockIdx.x << 10;

  // B fragments (U), 2 K-steps x 8 col-tiles: elem j <-> U[k=ks*32+q*8+j][n=u*16+s]
  short8 bfrag[2][8];
  #pragma unroll
  for (int ks = 0; ks < 2; ++ks)
    #pragma unroll
    for (int u = 0; u < 8; ++u)
      bfrag[ks][u] = *(const short8*)(Ut + (u*16 + s)*64 + ks*32 + q*8);

  float cv[8];
  #pragma unroll
  for (int u = 0; u < 8; ++u) cv[u] = cvec[u*16 + s];

  // wave w streams rows [n0 + w*256, +256) as 16 tiles of 16 rows
  const float* base = x + ((size_t)(n0 + w*256 + s))*64 + q*8;

  float4 c0 = *(const float4*)(base);
  float4 c1 = *(const float4*)(base + 4);
  float4 c2 = *(const float4*)(base + 32);
  float4 c3 = *(const float4*)(base + 36);

  #pragma unroll 2
  for (int t = 0; t < 16; ++t) {
    // prefetch tile t+1 (clamped; last-iter reload hits L1)
    const float* pn = base + (size_t)((t < 15 ? t + 1 : 15)) * 1024;
    float4 p0 = *(const float4*)(pn);
    float4 p1 = *(const float4*)(pn + 4);
    float4 p2 = *(const float4*)(pn + 32);
    float4 p3 = *(const float4*)(pn + 36);

    // A fragments: elem j <-> A[m=s][k=q*8+j] (af1: k+32)
    short8 af0 = cvt_bf16x8(c0, c1);
    short8 af1 = cvt_bf16x8(c2, c3);

    float sl[4] = {0.f, 0.f, 0.f, 0.f};
    #pragma unroll
    for (int u = 0; u < 8; ++u) {
      floatx4 acc = {cv[u], cv[u], cv[u], cv[u]};   // column const folded into C init
      acc = __builtin_amdgcn_mfma_f32_16x16x32_bf16(af0, bfrag[0][u], acc, 0, 0, 0);
      acc = __builtin_amdgcn_mfma_f32_16x16x32_bf16(af1, bfrag[1][u], acc, 0, 0, 0);
      #pragma unroll
      for (int r = 0; r < 4; ++r) sl[r] = fmaf(acc[r], acc[r], sl[r]);
    }

    // reduce over the 16 cols this lane group covers (lane bits 0..3)
    #pragma unroll
    for (int r = 0; r < 4; ++r) {
      float p = sl[r];
      p += __shfl_xor(p, 1, 64);
      p += __shfl_xor(p, 2, 64);
      p += __shfl_xor(p, 4, 64);
      p += __shfl_xor(p, 8, 64);
      sl[r] = -0.5f * p;
    }
    if (s == 0) {
      const int row0 = w*256 + t*16;
      float4 st = make_float4(sl[0], sl[1], sl[2], sl[3]);
      *(float4*)&lws[row0 + q*4] = st;   // samples row0+q*4 .. +3
    }

    c0 = p0; c1 = p1; c2 = p2; c3 = p3;
  }

  __syncthreads();
  // softmax-weighted mean over the block's 1024 lw values
  float4 mv = ((const float4*)lws)[tid];
  float mx = fmaxf(fmaxf(mv.x, mv.y), fmaxf(mv.z, mv.w));
  #pragma unroll
  for (int m = 1; m < 64; m <<= 1) mx = fmaxf(mx, __shfl_xor(mx, m, 64));
  if (l == 0) wredA[w] = mx;
  __syncthreads();
  const float bmax = fmaxf(fmaxf(wredA[0], wredA[1]), fmaxf(wredA[2], wredA[3]));

  float s1 = 0.f, s2 = 0.f, e;
  e = __expf(mv.x - bmax); s1 += e; s2 = fmaf(e, mv.x, s2);
  e = __expf(mv.y - bmax); s1 += e; s2 = fmaf(e, mv.y, s2);
  e = __expf(mv.z - bmax); s1 += e; s2 = fmaf(e, mv.z, s2);
  e = __expf(mv.w - bmax); s1 += e; s2 = fmaf(e, mv.w, s2);
  #pragma unroll
  for (int m = 1; m < 64; m <<= 1) {
    s1 += __shfl_xor(s1, m, 64);
    s2 += __shfl_xor(s2, m, 64);
  }
  if (l == 0) { wredB[w] = s1; wredC[w] = s2; }
  __syncthreads();
  if (tid == 0) {
    float S1 = wredB[0] + wredB[1] + wredB[2] + wredB[3];
    float S2 = wredC[0] + wredC[1] + wredC[2] + wredC[3];
    rbuf[blockIdx.x] = S2 / S1;
    __threadfence();                        // release: rbuf store visible device-wide
    unsigned int prev = atomicAdd(ctr, 1u); // device-scope ticket
    lastflag = (prev == 1023u) ? 1 : 0;
  }
  __syncthreads();

  if (lastflag) {
    // fused finish: deterministic reduction of the 1024 row results
    __threadfence();                        // acquire: invalidate stale L1/L2 lines
    float4 vv = ((const float4*)rbuf)[tid]; // 256 threads x 4 = 1024
    float ss = vv.x + vv.y + vv.z + vv.w;
    #pragma unroll
    for (int m = 1; m < 64; m <<= 1) ss += __shfl_xor(ss, m, 64);
    if (l == 0) wredB[w] = ss;
    __syncthreads();
    if (tid == 0)
      out[0] = -(wredB[0] + wredB[1] + wredB[2] + wredB[3]) * (1.0f / 1024.0f);
  }
}

extern "C" void kernel_launch(void* const* d_in, const int* in_sizes, int n_in,
                              void* d_out, int out_size, void* d_ws, size_t ws_size,
                              hipStream_t stream) {
  const float* x  = (const float*)d_in[0];
  const float* A  = (const float*)d_in[1];
  const float* b  = (const float*)d_in[2];
  const float* th = (const float*)d_in[3];
  char* ws = (char*)d_ws;
  unsigned short* Ut = (unsigned short*)(ws + WS_UT);
  float* cvec = (float*)(ws + WS_CV);
  float* rbuf = (float*)(ws + WS_R);
  unsigned int* ctr = (unsigned int*)(ws + WS_CTR);
  float* out  = (float*)d_out;

  prep_kernel<<<32, 256, 0, stream>>>(A, b, th, Ut, cvec, ctr);
  main_kernel<<<1024, 256, 0, stream>>>(x, Ut, cvec, rbuf, ctr, out);
}

// Round 3
// 368.858 us; speedup vs baseline: 1.1329x; 1.1329x over previous
//
#include <hip/hip_runtime.h>
#include <hip/hip_bf16.h>

// lw(x) = -0.5 * ( ||x(I-A) - b||^2 + ||xA + (b - theta)||^2 )
// i.e. G = x . U with U = [I-A | A]  (64 x 128),  column consts cvec = [-b | b-theta]
// lw = -0.5 * sum_n (G[n] + cvec[n])^2, with cvec folded into the MFMA accumulator init.
// ELBO = -(1/1024) * sum_rows softmax-weighted mean of lw over 1024 consecutive samples.
//
// R3: main_kernel was latency-bound (MfmaUtil 4%, VALUBusy 6%, HBM 10%, occ 26%).
//  - 512 threads/block (8 waves x 8 tiles) instead of 256 (4 waves x 16 tiles):
//    doubles resident waves, halves each wave's serial dependent-load chain.
//  - Fused finish reverted (R2 showed neutral-to-negative; per-block device fences
//    emit L2 writebacks on multi-XCD gfx950). Back to known-good 3-kernel tail.

typedef __attribute__((ext_vector_type(8))) short short8;   // 8 bf16 = 4 VGPRs (MFMA A/B frag)
typedef __attribute__((ext_vector_type(4))) float floatx4;  // MFMA C/D frag

#define WS_UT 0        // ushort[128*64] : U^T bf16, Ut[n*64+k] = U[k][n]
#define WS_CV 16384    // float[128]     : column constants
#define WS_R  17920    // float[1024]    : per-softmax-row results

__device__ __forceinline__ short bf16r(float f) {
  __hip_bfloat16 h = __float2bfloat16(f);   // RNE
  short r; __builtin_memcpy(&r, &h, 2); return r;
}

__device__ __forceinline__ short8 cvt_bf16x8(float4 a, float4 b) {
  short8 r;
  r[0]=bf16r(a.x); r[1]=bf16r(a.y); r[2]=bf16r(a.z); r[3]=bf16r(a.w);
  r[4]=bf16r(b.x); r[5]=bf16r(b.y); r[6]=bf16r(b.z); r[7]=bf16r(b.w);
  return r;
}

__global__ void prep_kernel(const float* __restrict__ A, const float* __restrict__ b,
                            const float* __restrict__ th,
                            unsigned short* __restrict__ Ut, float* __restrict__ cvec) {
  const int i = blockIdx.x * 256 + threadIdx.x;   // 8192 threads: k = i>>7, n = i&127
  const int k = i >> 7, n = i & 127;
  float u;
  if (n < 64) u = (k == n ? 1.f : 0.f) - A[k*64 + n];
  else        u = A[k*64 + (n - 64)];
  __hip_bfloat16 h = __float2bfloat16(u);
  unsigned short us; __builtin_memcpy(&us, &h, 2);
  Ut[n*64 + k] = us;                               // transposed for contiguous B-frag loads
  if (i < 128) cvec[i] = (i < 64) ? -b[i] : (b[i - 64] - th[i - 64]);
}

// One block per softmax row (1024 samples). 512 threads = 8 waves; each wave does
// 8 tiles of 16 samples. MFMA 16x16x32 bf16: A = x tile, B = U (resident in regs).
__global__ __launch_bounds__(512) void main_kernel(
    const float* __restrict__ x, const unsigned short* __restrict__ Ut,
    const float* __restrict__ cvec, float* __restrict__ rbuf) {
  __shared__ __align__(16) float lws[1024];
  __shared__ float wredA[8], wredB[8], wredC[8];

  const int tid = threadIdx.x;
  const int w = tid >> 6, l = tid & 63, q = l >> 4, s = l & 15;
  const int n0 = blockIdx.x << 10;

  // B fragments (U), 2 K-steps x 8 col-tiles: elem j <-> U[k=ks*32+q*8+j][n=u*16+s]
  short8 bfrag[2][8];
  #pragma unroll
  for (int ks = 0; ks < 2; ++ks)
    #pragma unroll
    for (int u = 0; u < 8; ++u)
      bfrag[ks][u] = *(const short8*)(Ut + (u*16 + s)*64 + ks*32 + q*8);

  float cv[8];
  #pragma unroll
  for (int u = 0; u < 8; ++u) cv[u] = cvec[u*16 + s];

  // wave w streams rows [n0 + w*128, +128) as 8 tiles of 16 rows
  const float* base = x + ((size_t)(n0 + w*128 + s))*64 + q*8;

  float4 c0 = *(const float4*)(base);
  float4 c1 = *(const float4*)(base + 4);
  float4 c2 = *(const float4*)(base + 32);
  float4 c3 = *(const float4*)(base + 36);

  #pragma unroll 2
  for (int t = 0; t < 8; ++t) {
    // prefetch tile t+1 (clamped; last-iter reload hits L1)
    const float* pn = base + (size_t)((t < 7 ? t + 1 : 7)) * 1024;
    float4 p0 = *(const float4*)(pn);
    float4 p1 = *(const float4*)(pn + 4);
    float4 p2 = *(const float4*)(pn + 32);
    float4 p3 = *(const float4*)(pn + 36);

    // A fragments: elem j <-> A[m=s][k=q*8+j] (af1: k+32)
    short8 af0 = cvt_bf16x8(c0, c1);
    short8 af1 = cvt_bf16x8(c2, c3);

    float sl[4] = {0.f, 0.f, 0.f, 0.f};
    #pragma unroll
    for (int u = 0; u < 8; ++u) {
      floatx4 acc = {cv[u], cv[u], cv[u], cv[u]};   // column const folded into C init
      acc = __builtin_amdgcn_mfma_f32_16x16x32_bf16(af0, bfrag[0][u], acc, 0, 0, 0);
      acc = __builtin_amdgcn_mfma_f32_16x16x32_bf16(af1, bfrag[1][u], acc, 0, 0, 0);
      #pragma unroll
      for (int r = 0; r < 4; ++r) sl[r] = fmaf(acc[r], acc[r], sl[r]);
    }

    // reduce over the 16 cols this lane group covers (lane bits 0..3)
    #pragma unroll
    for (int r = 0; r < 4; ++r) {
      float p = sl[r];
      p += __shfl_xor(p, 1, 64);
      p += __shfl_xor(p, 2, 64);
      p += __shfl_xor(p, 4, 64);
      p += __shfl_xor(p, 8, 64);
      sl[r] = -0.5f * p;
    }
    if (s == 0) {
      const int row0 = w*128 + t*16;
      float4 st = make_float4(sl[0], sl[1], sl[2], sl[3]);
      *(float4*)&lws[row0 + q*4] = st;   // samples row0+q*4 .. +3
    }

    c0 = p0; c1 = p1; c2 = p2; c3 = p3;
  }

  __syncthreads();
  // softmax-weighted mean over the block's 1024 lw values (512 threads x 2)
  float2 mv = ((const float2*)lws)[tid];
  float mx = fmaxf(mv.x, mv.y);
  #pragma unroll
  for (int m = 1; m < 64; m <<= 1) mx = fmaxf(mx, __shfl_xor(mx, m, 64));
  if (l == 0) wredA[w] = mx;
  __syncthreads();
  float bmax = wredA[0];
  #pragma unroll
  for (int i = 1; i < 8; ++i) bmax = fmaxf(bmax, wredA[i]);

  float s1 = 0.f, s2 = 0.f, e;
  e = __expf(mv.x - bmax); s1 += e; s2 = fmaf(e, mv.x, s2);
  e = __expf(mv.y - bmax); s1 += e; s2 = fmaf(e, mv.y, s2);
  #pragma unroll
  for (int m = 1; m < 64; m <<= 1) {
    s1 += __shfl_xor(s1, m, 64);
    s2 += __shfl_xor(s2, m, 64);
  }
  if (l == 0) { wredB[w] = s1; wredC[w] = s2; }
  __syncthreads();
  if (tid == 0) {
    float S1 = 0.f, S2 = 0.f;
    #pragma unroll
    for (int i = 0; i < 8; ++i) { S1 += wredB[i]; S2 += wredC[i]; }
    rbuf[blockIdx.x] = S2 / S1;
  }
}

__global__ void finish_kernel(const float* __restrict__ rbuf, float* __restrict__ out) {
  __shared__ float wsum[4];
  const int tid = threadIdx.x;
  float4 vv = ((const float4*)rbuf)[tid];     // 256 threads x 4 = 1024
  float s = vv.x + vv.y + vv.z + vv.w;
  #pragma unroll
  for (int m = 1; m < 64; m <<= 1) s += __shfl_xor(s, m, 64);
  if ((tid & 63) == 0) wsum[tid >> 6] = s;
  __syncthreads();
  if (tid == 0) out[0] = -(wsum[0] + wsum[1] + wsum[2] + wsum[3]) * (1.0f / 1024.0f);
}

extern "C" void kernel_launch(void* const* d_in, const int* in_sizes, int n_in,
                              void* d_out, int out_size, void* d_ws, size_t ws_size,
                              hipStream_t stream) {
  const float* x  = (const float*)d_in[0];
  const float* A  = (const float*)d_in[1];
  const float* b  = (const float*)d_in[2];
  const float* th = (const float*)d_in[3];
  char* ws = (char*)d_ws;
  unsigned short* Ut = (unsigned short*)(ws + WS_UT);
  float* cvec = (float*)(ws + WS_CV);
  float* rbuf = (float*)(ws + WS_R);
  float* out  = (float*)d_out;

  prep_kernel<<<32, 256, 0, stream>>>(A, b, th, Ut, cvec);
  main_kernel<<<1024, 512, 0, stream>>>(x, Ut, cvec, rbuf);
  finish_kernel<<<1, 256, 0, stream>>>(rbuf, out);
}